// Round 2
// baseline (2729.358 us; speedup 1.0000x reference)
//
#include <hip/hip_runtime.h>
#include <hip/hip_bf16.h>

#define B_ 128
#define C_ 1024

typedef float f32x4 __attribute__((ext_vector_type(4)));
typedef short bf16x8 __attribute__((ext_vector_type(8)));

__device__ inline unsigned short f2bf(float x){
  unsigned u = __float_as_uint(x);
  return (unsigned short)((u + 0x7fffu + ((u>>16)&1u)) >> 16);
}
__device__ inline unsigned long long pack4(float a,float b,float c,float d){
  unsigned lo = (unsigned)f2bf(a) | ((unsigned)f2bf(b)<<16);
  unsigned hi = (unsigned)f2bf(c) | ((unsigned)f2bf(d)<<16);
  return (unsigned long long)lo | ((unsigned long long)hi<<32);
}
__device__ inline float sigm(float x){ return 1.f/(1.f+expf(-x)); }
__device__ inline float wsum(float v){
  #pragma unroll
  for(int o=32;o;o>>=1) v += __shfl_xor(v,o);
  return v;
}
// LDS swizzles (u16 index units). XOR row bits into 16B-slot bits.
__device__ inline int swz64(int r,int c){ return (r*64+c) ^ ((r&7)<<3); }
__device__ inline int swz128(int r,int c){ return (r*128+c) ^ ((r&7)<<3); }

// ---- stage A: 128x64 bf16 tile from global (lda in elems) into lA (swz64) ----
__device__ __forceinline__ void stageA(unsigned short* lA, const unsigned short* __restrict__ A,
                                       int lda, int k0){
  int tid = threadIdx.x;
  #pragma unroll
  for (int p=0;p<8;++p){
    int idx = tid + p*256; int m = idx>>4; int c4 = (idx&15)<<2;
    *(unsigned long long*)&lA[swz64(m,c4)] = *(const unsigned long long*)(A + m*lda + k0 + c4);
  }
}
// ---- stage B: W f32 [k][cols ldw], tile 64k x NC -> lB[n][k] bf16 (swz128) ----
template<int NC>
__device__ __forceinline__ void stageB(unsigned short* lB, const float* __restrict__ W,
                                       int ldw, int wcol, int k0){
  int tid = threadIdx.x;
  int n = tid & (NC-1), kp = tid / NC;
  constexpr int KPP = 512/NC;
  #pragma unroll
  for (int p=0;p<NC/8;++p){
    int kl = p*KPP + kp*2;
    const float* wp = W + (size_t)(k0+kl)*ldw + wcol + n;
    unsigned pk = (unsigned)f2bf(wp[0]) | ((unsigned)f2bf(wp[ldw])<<16);
    *(unsigned*)&lB[swz128(n,kl)] = pk;
  }
}
// ---- stage B transposed: W f32 [16][1024] row-major -> lB[n][k] ----
__device__ __forceinline__ void stageBt16(unsigned short* lB, const float* __restrict__ W, int k0){
  int tid = threadIdx.x; int n = tid&15, kp = tid>>4;
  #pragma unroll
  for (int p=0;p<2;++p){
    int kl = p*32 + kp*2;
    const float* wp = W + (size_t)n*1024 + k0 + kl;
    unsigned pk = (unsigned)f2bf(wp[0]) | ((unsigned)f2bf(wp[1])<<16);
    *(unsigned*)&lB[swz128(n,kl)] = pk;
  }
}
// ---- one BK=64 MFMA step: acc[2][NF] over 128 rows x NF*16 cols ----
template<int NF>
__device__ __forceinline__ void mfma_step(const unsigned short* lA, const unsigned short* lB,
                                          f32x4 (&acc)[2][NF]){
  int tid=threadIdx.x, lane=tid&63, w=tid>>6, lo=lane&15, hi=lane>>4;
  #pragma unroll
  for (int ks=0;ks<2;++ks){
    int kk = ks*32 + hi*8;
    bf16x8 a0 = *(const bf16x8*)&lA[swz64(w*32+lo, kk)];
    bf16x8 a1 = *(const bf16x8*)&lA[swz64(w*32+16+lo, kk)];
    #pragma unroll
    for (int nf=0;nf<NF;++nf){
      bf16x8 b = *(const bf16x8*)&lB[swz128(nf*16+lo, kk)];
      acc[0][nf] = __builtin_amdgcn_mfma_f32_16x16x32_bf16(a0,b,acc[0][nf],0,0,0);
      acc[1][nf] = __builtin_amdgcn_mfma_f32_16x16x32_bf16(a1,b,acc[1][nf],0,0,0);
    }
  }
}

// ---------------- time-mix prep: LN + 8-way lerp -> bf16 mixed[8][B][C] ----------------
__launch_bounds__(256)
__global__ void tmix_prep(const float* __restrict__ x, const float* __restrict__ lnw,
                          const float* __restrict__ lnb, const float* __restrict__ lerp8,
                          const float* __restrict__ xs, unsigned short* __restrict__ mixed){
  int b = blockIdx.x, tid = threadIdx.x;
  f32x4 v = ((const f32x4*)(x + b*C_))[tid];
  float s  = v[0]+v[1]+v[2]+v[3];
  float ss = v[0]*v[0]+v[1]*v[1]+v[2]*v[2]+v[3]*v[3];
  __shared__ float red[8];
  s = wsum(s); ss = wsum(ss);
  int lane = tid&63, wv = tid>>6;
  if (lane==0){ red[wv]=s; red[4+wv]=ss; }
  __syncthreads();
  float S1 = red[0]+red[1]+red[2]+red[3];
  float S2 = red[4]+red[5]+red[6]+red[7];
  float m = S1*(1.f/C_);
  float var = S2*(1.f/C_) - m*m;
  float inv = rsqrtf(var + 1e-5f);
  int c0 = tid*4;
  float xl[4], xsv[4];
  #pragma unroll
  for(int j=0;j<4;++j){
    xl[j]  = (v[j]-m)*inv*lnw[c0+j] + lnb[c0+j];
    xsv[j] = xs[b*C_ + c0 + j];
  }
  #pragma unroll
  for(int jj=0;jj<8;++jj){
    float o[4];
    #pragma unroll
    for(int j=0;j<4;++j){
      float t = lerp8[jj*C_ + c0 + j];
      o[j] = xl[j] + t*(xsv[j]-xl[j]);
    }
    *(unsigned long long*)&mixed[jj*(B_*C_) + b*C_ + c0] = pack4(o[0],o[1],o[2],o[3]);
  }
}

// ---------------- channel-mix prep ----------------
__launch_bounds__(256)
__global__ void cmix_prep(const float* __restrict__ x, const float* __restrict__ lnw,
                          const float* __restrict__ lnb, const float* __restrict__ lk,
                          const float* __restrict__ xs, unsigned short* __restrict__ out){
  int b = blockIdx.x, tid = threadIdx.x;
  f32x4 v = ((const f32x4*)(x + b*C_))[tid];
  float s  = v[0]+v[1]+v[2]+v[3];
  float ss = v[0]*v[0]+v[1]*v[1]+v[2]*v[2]+v[3]*v[3];
  __shared__ float red[8];
  s = wsum(s); ss = wsum(ss);
  int lane = tid&63, wv = tid>>6;
  if (lane==0){ red[wv]=s; red[4+wv]=ss; }
  __syncthreads();
  float S1 = red[0]+red[1]+red[2]+red[3];
  float S2 = red[4]+red[5]+red[6]+red[7];
  float m = S1*(1.f/C_);
  float var = S2*(1.f/C_) - m*m;
  float inv = rsqrtf(var + 1e-5f);
  int c0 = tid*4;
  float o[4];
  #pragma unroll
  for(int j=0;j<4;++j){
    float xl = (v[j]-m)*inv*lnw[c0+j] + lnb[c0+j];
    float t = lk[c0+j];
    o[j] = xl + t*(xs[b*C_+c0+j]-xl);
  }
  *(unsigned long long*)&out[b*C_ + c0] = pack4(o[0],o[1],o[2],o[3]);
}

// ---------------- mega GEMM1: r/k/v tiles + ks/vs scores + fused 2-stage LoRAs ----------------
struct M1Args {
  const unsigned short* mixed;
  const float *Wr,*Wk,*Wv;
  const float *ksW,*vsW,*ksb,*vsb;
  const float *vA,*vB,*vbias,*aA,*aB,*abias,*dA,*dB,*dbias,*gA,*gB;
  float *g1o,*ksig,*vsig,*vm,*afin,*wfin,*gfin;
};

// TYPE: 0=v,1=a,2=d,3=g.  KD = LoRA dim. NB = blocks for this type.
template<int KD, int TYPE, int NB>
__device__ void lora_block(int slice, unsigned short* lA, unsigned short* lB,
                           unsigned short* pbf, const M1Args& a){
  int tid=threadIdx.x, lane=tid&63, w=tid>>6, lo=lane&15, hi=lane>>4;
  const float* W1 = TYPE==0?a.vA : TYPE==1?a.aA : TYPE==2?a.dA : a.gA;
  const float* W2 = TYPE==0?a.vB : TYPE==1?a.aB : TYPE==2?a.dB : a.gB;
  const int asel  = TYPE==0?2 : TYPE==1?4 : TYPE==2?3 : 5;
  const unsigned short* A = a.mixed + asel*(B_*C_);
  // stage1: [128][KD] = mixed @ W1
  f32x4 acc1[2][KD/16] = {};
  for (int kb=0;kb<16;++kb){
    stageA(lA, A, 1024, kb*64);
    stageB<KD>(lB, W1, KD, 0, kb*64);
    __syncthreads();
    mfma_step<KD/16>(lA,lB,acc1);
    __syncthreads();
  }
  #pragma unroll
  for (int mf=0;mf<2;++mf)
  #pragma unroll
  for (int nf=0;nf<KD/16;++nf)
  #pragma unroll
  for (int i=0;i<4;++i){
    int row = w*32+mf*16+hi*4+i, col = nf*16+lo;
    float x = acc1[mf][nf][i];
    if (TYPE==2) x = tanhf(x);
    if (TYPE==3) x = sigm(x);
    pbf[swz128(row,col)] = f2bf(x);
  }
  __syncthreads();
  // stage2: cols [slice*1024/NB ...) in 32-col chunks, K=KD from pbf
  constexpr int NCOL = 1024/NB;
  for (int cc=0; cc<NCOL/32; ++cc){
    int colb = slice*NCOL + cc*32;
    {
      int n2 = tid&31, kp2 = tid>>5;
      #pragma unroll
      for (int p=0;p<KD/16;++p){
        int kl = p*16 + kp2*2;
        const float* wp = W2 + (size_t)kl*1024 + colb + n2;
        unsigned pk = (unsigned)f2bf(wp[0]) | ((unsigned)f2bf(wp[1024])<<16);
        *(unsigned*)&lB[swz128(n2,kl)] = pk;
      }
    }
    __syncthreads();
    f32x4 acc2[2][2] = {};
    #pragma unroll
    for (int ks=0;ks<KD/32;++ks){
      int kk = ks*32 + hi*8;
      bf16x8 a0 = *(const bf16x8*)&pbf[swz128(w*32+lo, kk)];
      bf16x8 a1 = *(const bf16x8*)&pbf[swz128(w*32+16+lo, kk)];
      #pragma unroll
      for (int nf=0;nf<2;++nf){
        bf16x8 b = *(const bf16x8*)&lB[swz128(nf*16+lo, kk)];
        acc2[0][nf] = __builtin_amdgcn_mfma_f32_16x16x32_bf16(a0,b,acc2[0][nf],0,0,0);
        acc2[1][nf] = __builtin_amdgcn_mfma_f32_16x16x32_bf16(a1,b,acc2[1][nf],0,0,0);
      }
    }
    #pragma unroll
    for (int mf=0;mf<2;++mf)
    #pragma unroll
    for (int nf=0;nf<2;++nf)
    #pragma unroll
    for (int i=0;i<4;++i){
      int row = w*32+mf*16+hi*4+i;
      int col = colb + nf*16 + lo;
      float x = acc2[mf][nf][i];
      int o = row*C_ + col;
      if (TYPE==0)      a.vm[o]   = sigm(x + a.vbias[col]);
      else if (TYPE==1) a.afin[o] = sigm(x + a.abias[col]);
      else if (TYPE==2){ float d = x + a.dbias[col]; float sp = log1pf(expf(-d));
                         a.wfin[o] = expf(-expf(-0.5f - sp)); }
      else              a.gfin[o] = x;
    }
    __syncthreads();
  }
}

__launch_bounds__(256)
__global__ void mega1_k(M1Args a){
  __shared__ unsigned short lA[128*64];
  __shared__ unsigned short lB[128*128];
  __shared__ unsigned short pbf[128*128];
  int t = blockIdx.x;
  int tid=threadIdx.x, lane=tid&63, w=tid>>6, lo=lane&15, hi=lane>>4;
  if (t < 192){
    int mat = t>>6, tile = t&63, wcol = tile*16;
    const float* W = mat==0?a.Wr:(mat==1?a.Wk:a.Wv);
    const unsigned short* A = a.mixed + mat*(B_*C_);
    f32x4 acc[2][1] = {};
    for (int kb=0;kb<16;++kb){
      stageA(lA, A, 1024, kb*64);
      stageB<16>(lB, W, 1024, wcol, kb*64);
      __syncthreads();
      mfma_step<1>(lA,lB,acc);
      __syncthreads();
    }
    float* o = a.g1o + mat*1024 + wcol + lo;
    #pragma unroll
    for (int mf=0;mf<2;++mf)
    #pragma unroll
    for (int i=0;i<4;++i){
      int row = w*32+mf*16+hi*4+i;
      o[row*3072] = acc[mf][0][i];
    }
  } else if (t < 194){
    int s = t-192;
    const float* W   = s? a.vsW : a.ksW;
    const float* bia = s? a.vsb : a.ksb;
    float* out       = s? a.vsig : a.ksig;
    const unsigned short* A = a.mixed + (6+s)*(B_*C_);
    f32x4 acc[2][1] = {};
    for (int kb=0;kb<16;++kb){
      stageA(lA, A, 1024, kb*64);
      stageBt16(lB, W, kb*64);
      __syncthreads();
      mfma_step<1>(lA,lB,acc);
      __syncthreads();
    }
    #pragma unroll
    for (int mf=0;mf<2;++mf)
    #pragma unroll
    for (int i=0;i<4;++i){
      int row = w*32+mf*16+hi*4+i;
      out[row*16 + lo] = sigm(acc[mf][0][i] + bia[lo]);
    }
  }
  else if (t==194) lora_block<32,0,1>(0,     lA,lB,pbf, a);
  else if (t<197)  lora_block<64,1,2>(t-195, lA,lB,pbf, a);
  else if (t<199)  lora_block<64,2,2>(t-197, lA,lB,pbf, a);
  else             lora_block<128,3,4>(t-199,lA,lB,pbf, a);
}

// ---------------- state kernel: one wave per (b,h) ----------------
__launch_bounds__(256)
__global__ void state_k(const float* __restrict__ g1, const float* __restrict__ vm,
                        const float* __restrict__ afin, const float* __restrict__ wfin,
                        const float* __restrict__ gfin, const float* __restrict__ ksig,
                        const float* __restrict__ vsig, const float* __restrict__ S,
                        const float* __restrict__ bon, const float* __restrict__ gnw,
                        const float* __restrict__ gnb, float* __restrict__ v0,
                        int first, unsigned short* __restrict__ y){
  __shared__ __align__(16) float lt[4][2][64];
  int wv = threadIdx.x>>6, lane = threadIdx.x&63;
  int pair = blockIdx.x*4 + wv;
  int b = pair>>4, h = pair&15;
  const float* g1r = g1 + b*3072;
  int ci = h*64 + lane;
  float r   = g1r[ci];
  float k   = g1r[1024+ci];
  float vwv = g1r[2048+ci];
  float v;
  if (first){ v = vwv; v0[b*C_+ci] = vwv; }
  else { float vmv = vm[b*C_+ci]; v = vwv + vmv*(v0[b*C_+ci] - vwv); }
  float aa = afin[b*C_+ci];
  float ww = wfin[b*C_+ci];
  float gg = gfin[b*C_+ci];
  float ks = ksig[b*16+h];
  float vs = vsig[b*16+h];
  float nk = sqrtf(wsum(k*k));
  float kkv = ks * k / fmaxf(nk, 1e-12f);
  float nv = sqrtf(wsum(v*v));
  float vh = vs * v / fmaxf(nv, 1e-12f);
  float kh = kkv * aa;
  float khrh = wsum(kh*r);
  float bkr  = wsum(r * bon[h*64+lane] * kh);
  lt[wv][0][lane] = ww*r;
  lt[wv][1][lane] = kkv;
  __syncthreads();
  const float* Sr = S + ((size_t)((b*16+h)*64 + lane))*64;
  float s1=0.f, s2=0.f;
  #pragma unroll
  for (int j=0;j<16;++j){
    f32x4 sv = *(const f32x4*)&Sr[j*4];
    f32x4 u1 = *(const f32x4*)&lt[wv][0][j*4];
    f32x4 u2 = *(const f32x4*)&lt[wv][1][j*4];
    s1 += sv[0]*u1[0]+sv[1]*u1[1]+sv[2]*u1[2]+sv[3]*u1[3];
    s2 += sv[0]*u2[0]+sv[1]*u2[1]+sv[2]*u2[2]+sv[3]*u2[3];
  }
  float out = s1 + (vh - s2)*khrh;
  float mu = wsum(out)*(1.f/64.f);
  float dev = out - mu;
  float var = wsum(dev*dev)*(1.f/64.f);
  float gn = dev*rsqrtf(var + 6.4e-4f)*gnw[ci] + gnb[ci];
  float yv = gg*(gn + bkr*vh);
  y[b*C_+ci] = f2bf(yv);
}

// ---------------- Wo GEMM: full-K, epilogue adds onto residual in-place ----------------
__launch_bounds__(256)
__global__ void wo_k(const unsigned short* __restrict__ y, const float* __restrict__ W,
                     float* __restrict__ xbuf){
  __shared__ unsigned short lA[128*64];
  __shared__ unsigned short lB[32*128];
  int wcol = blockIdx.x*16;
  int tid=threadIdx.x, lane=tid&63, w=tid>>6, lo=lane&15, hi=lane>>4;
  f32x4 acc[2][1] = {};
  for (int kb=0;kb<16;++kb){
    stageA(lA, y, 1024, kb*64);
    stageB<16>(lB, W, 1024, wcol, kb*64);
    __syncthreads();
    mfma_step<1>(lA,lB,acc);
    __syncthreads();
  }
  #pragma unroll
  for (int mf=0;mf<2;++mf)
  #pragma unroll
  for (int i=0;i<4;++i){
    int row = w*32+mf*16+hi*4+i;
    int o = row*C_ + wcol + lo;
    xbuf[o] += acc[mf][0][i];
  }
}

// ---------------- cW_k GEMM: full-K, relu^2 epilogue -> bf16 h2 ----------------
__launch_bounds__(256)
__global__ void cwk_k(const unsigned short* __restrict__ A, const float* __restrict__ W,
                      unsigned short* __restrict__ h2){
  __shared__ unsigned short lA[128*64];
  __shared__ unsigned short lB[32*128];
  int wcol = blockIdx.x*16;
  int tid=threadIdx.x, lane=tid&63, w=tid>>6, lo=lane&15, hi=lane>>4;
  f32x4 acc[2][1] = {};
  for (int kb=0;kb<16;++kb){
    stageA(lA, A, 1024, kb*64);
    stageB<16>(lB, W, 4096, wcol, kb*64);
    __syncthreads();
    mfma_step<1>(lA,lB,acc);
    __syncthreads();
  }
  #pragma unroll
  for (int mf=0;mf<2;++mf)
  #pragma unroll
  for (int i=0;i<4;++i){
    int row = w*32+mf*16+hi*4+i;
    float r = fmaxf(acc[mf][0][i], 0.f);
    h2[row*4096 + wcol + lo] = f2bf(r*r);
  }
}

// ---------------- cW_v GEMM: split-K=4, atomic add onto residual ----------------
__launch_bounds__(256)
__global__ void cwv_k(const unsigned short* __restrict__ A, const float* __restrict__ W,
                      float* __restrict__ xbuf){
  __shared__ unsigned short lA[128*64];
  __shared__ unsigned short lB[32*128];
  int wcol = blockIdx.x*16;
  int kbase = blockIdx.y*1024;
  int tid=threadIdx.x, lane=tid&63, w=tid>>6, lo=lane&15, hi=lane>>4;
  f32x4 acc[2][1] = {};
  for (int kb=0;kb<16;++kb){
    stageA(lA, A, 4096, kbase + kb*64);
    stageB<16>(lB, W, 1024, wcol, kbase + kb*64);
    __syncthreads();
    mfma_step<1>(lA,lB,acc);
    __syncthreads();
  }
  #pragma unroll
  for (int mf=0;mf<2;++mf)
  #pragma unroll
  for (int i=0;i<4;++i){
    int row = w*32+mf*16+hi*4+i;
    unsafeAtomicAdd(&xbuf[row*C_ + wcol + lo], acc[mf][0][i]);
  }
}

extern "C" void kernel_launch(void* const* d_in, const int* in_sizes, int n_in,
                              void* d_out, int out_size, void* d_ws, size_t ws_size,
                              hipStream_t stream){
  const float* in_BC  = (const float*)d_in[0];
  const float* txs    = (const float*)d_in[1];
  const float* tstate = (const float*)d_in[2];
  const float* cxs    = (const float*)d_in[3];
  const float* lntw   = (const float*)d_in[4];
  const float* lntb   = (const float*)d_in[5];
  const float* lerp8  = (const float*)d_in[6];
  const float* bon    = (const float*)d_in[7];
  const float* Wr     = (const float*)d_in[8];
  const float* Wk     = (const float*)d_in[9];
  const float* Wv     = (const float*)d_in[10];
  const float* Wo     = (const float*)d_in[11];
  const float* ksW    = (const float*)d_in[12];
  const float* ksb    = (const float*)d_in[13];
  const float* vsW    = (const float*)d_in[14];
  const float* vsb    = (const float*)d_in[15];
  const float* vA     = (const float*)d_in[16];
  const float* vBp    = (const float*)d_in[17];
  const float* vbias  = (const float*)d_in[18];
  const float* aA     = (const float*)d_in[19];
  const float* aB     = (const float*)d_in[20];
  const float* abias  = (const float*)d_in[21];
  const float* dA     = (const float*)d_in[22];
  const float* dB     = (const float*)d_in[23];
  const float* dbias  = (const float*)d_in[24];
  const float* gA     = (const float*)d_in[25];
  const float* gB     = (const float*)d_in[26];
  const float* gnw    = (const float*)d_in[27];
  const float* gnb    = (const float*)d_in[28];
  const float* lncw   = (const float*)d_in[29];
  const float* lncb   = (const float*)d_in[30];
  const float* lkc    = (const float*)d_in[31];
  const float* cWk    = (const float*)d_in[32];
  const float* cWv    = (const float*)d_in[33];

  char* ws = (char*)d_ws;
  float* xbuf          = (float*)(ws + 0x000000);          // 512K f32 residual
  unsigned short* mixed= (unsigned short*)(ws + 0x080000); // 2M  bf16 (8,B,C)
  float* g1o           = (float*)(ws + 0x280000);          // 1.5M f32 (B,3072) r|k|vwv
  float* ksig          = (float*)(ws + 0x400000);          // 8K
  float* vsig          = (float*)(ws + 0x402000);          // 8K
  float* vm            = (float*)(ws + 0x410000);          // 512K
  float* afin          = (float*)(ws + 0x490000);          // 512K
  float* wfin          = (float*)(ws + 0x510000);          // 512K
  float* gfin          = (float*)(ws + 0x590000);          // 512K
  float* v0            = (float*)(ws + 0x610000);          // 512K
  unsigned short* ybuf = (unsigned short*)(ws + 0x690000); // 256K bf16
  unsigned short* mixc = (unsigned short*)(ws + 0x6D0000); // 256K bf16
  unsigned short* h2   = (unsigned short*)(ws + 0x710000); // 1M bf16 (B,4096)

  hipMemcpyAsync(xbuf, in_BC, 524288, hipMemcpyDeviceToDevice, stream);
  for (int l=0; l<12; ++l){
    tmix_prep<<<128,256,0,stream>>>(xbuf, lntw+l*1024, lntb+l*1024, lerp8+l*8192,
                                    txs+l*131072, mixed);
    M1Args a1;
    a1.mixed = mixed;
    a1.Wr = Wr + (size_t)l*1048576; a1.Wk = Wk + (size_t)l*1048576; a1.Wv = Wv + (size_t)l*1048576;
    a1.ksW = ksW + l*16384; a1.vsW = vsW + l*16384; a1.ksb = ksb + l*16; a1.vsb = vsb + l*16;
    a1.vA = vA + l*32768;  a1.vB = vBp + l*32768;  a1.vbias = vbias + l*1024;
    a1.aA = aA + l*65536;  a1.aB = aB + l*65536;   a1.abias = abias + l*1024;
    a1.dA = dA + l*65536;  a1.dB = dB + l*65536;   a1.dbias = dbias + l*1024;
    a1.gA = gA + l*131072; a1.gB = gB + l*131072;
    a1.g1o = g1o; a1.ksig = ksig; a1.vsig = vsig;
    a1.vm = vm; a1.afin = afin; a1.wfin = wfin; a1.gfin = gfin;
    mega1_k<<<203,256,0,stream>>>(a1);
    state_k<<<512,256,0,stream>>>(g1o, vm, afin, wfin, gfin, ksig, vsig,
                                  tstate + (size_t)l*8388608, bon + l*1024,
                                  gnw + l*1024, gnb + l*1024, v0, (l==0)?1:0, ybuf);
    wo_k<<<64,256,0,stream>>>(ybuf, Wo + (size_t)l*1048576, xbuf);
    cmix_prep<<<128,256,0,stream>>>(xbuf, lncw+l*1024, lncb+l*1024, lkc+l*1024,
                                    cxs+l*131072, mixc);
    cwk_k<<<256,256,0,stream>>>(mixc, cWk + (size_t)l*4194304, h2);
    cwv_k<<<dim3(64,4),256,0,stream>>>(h2, cWv + (size_t)l*4194304, xbuf);
  }
  hipMemcpyAsync(d_out, xbuf, 524288, hipMemcpyDeviceToDevice, stream);
}

// Round 3
// 1628.216 us; speedup vs baseline: 1.6763x; 1.6763x over previous
//
#include <hip/hip_runtime.h>
#include <hip/hip_bf16.h>

#define B_ 128
#define C_ 1024
#define LD1 3392

typedef float f32x4 __attribute__((ext_vector_type(4)));
typedef short bf16x8 __attribute__((ext_vector_type(8)));

__device__ inline unsigned short f2bf(float x){
  unsigned u = __float_as_uint(x);
  return (unsigned short)((u + 0x7fffu + ((u>>16)&1u)) >> 16);
}
__device__ inline unsigned long long pack4(float a,float b,float c,float d){
  unsigned lo = (unsigned)f2bf(a) | ((unsigned)f2bf(b)<<16);
  unsigned hi = (unsigned)f2bf(c) | ((unsigned)f2bf(d)<<16);
  return (unsigned long long)lo | ((unsigned long long)hi<<32);
}
__device__ inline float sigm(float x){ return 1.f/(1.f+expf(-x)); }
__device__ inline float wsum(float v){
  #pragma unroll
  for(int o=32;o;o>>=1) v += __shfl_xor(v,o);
  return v;
}
__device__ inline int swz64(int r,int c){ return (r*64+c) ^ ((r&7)<<3); }
__device__ inline int swz128(int r,int c){ return (r*128+c) ^ ((r&7)<<3); }

// ---- one BK=64 MFMA step over 128 rows x 32 cols ----
__device__ __forceinline__ void mfma_step2(const unsigned short* lA, const unsigned short* lB,
                                           f32x4 (&acc)[2][2]){
  int tid=threadIdx.x, lane=tid&63, w=tid>>6, lo=lane&15, hi=lane>>4;
  #pragma unroll
  for (int ks=0;ks<2;++ks){
    int kk = ks*32 + hi*8;
    bf16x8 a0 = *(const bf16x8*)&lA[swz64(w*32+lo, kk)];
    bf16x8 a1 = *(const bf16x8*)&lA[swz64(w*32+16+lo, kk)];
    #pragma unroll
    for (int nf=0;nf<2;++nf){
      bf16x8 b = *(const bf16x8*)&lB[swz128(nf*16+lo, kk)];
      acc[0][nf] = __builtin_amdgcn_mfma_f32_16x16x32_bf16(a0,b,acc[0][nf],0,0,0);
      acc[1][nf] = __builtin_amdgcn_mfma_f32_16x16x32_bf16(a1,b,acc[1][nf],0,0,0);
    }
  }
}

// ---- register-prefetch pipelined GEMM: M=128, N=32, BK=64 ----
// AF32=1: A is f32 with fused relu^2 during staging. wtrans: W is [16][1024] row-major.
template<int AF32>
__device__ __forceinline__ void gemm_pipe(unsigned short* lA, unsigned short* lB,
    const void* __restrict__ Av, int lda,
    const float* __restrict__ W, int ldw, int wcol, int wtrans,
    int kt0, int kIters, f32x4 (&acc)[2][2])
{
  int tid = threadIdx.x;
  int n = tid&31, kp = tid>>5;
  unsigned long long ra[8];
  f32x4 raf[8];
  float rb[4][2];

  auto loadA = [&](int k0){
    #pragma unroll
    for (int p=0;p<8;++p){
      int idx = tid + p*256; int m = idx>>4; int c4 = (idx&15)<<2;
      if constexpr (AF32)
        raf[p] = *(const f32x4*)((const float*)Av + (size_t)m*lda + k0 + c4);
      else
        ra[p] = *(const unsigned long long*)((const unsigned short*)Av + (size_t)m*lda + k0 + c4);
    }
  };
  auto storeA = [&](){
    #pragma unroll
    for (int p=0;p<8;++p){
      int idx = tid + p*256; int m = idx>>4; int c4 = (idx&15)<<2;
      unsigned long long v;
      if constexpr (AF32){
        float e0=fmaxf(raf[p][0],0.f), e1=fmaxf(raf[p][1],0.f);
        float e2=fmaxf(raf[p][2],0.f), e3=fmaxf(raf[p][3],0.f);
        v = pack4(e0*e0, e1*e1, e2*e2, e3*e3);
      } else v = ra[p];
      *(unsigned long long*)&lA[swz64(m,c4)] = v;
    }
  };
  auto loadB = [&](int k0){
    #pragma unroll
    for (int p=0;p<4;++p){
      int kl = p*16 + kp*2;
      if (!wtrans){
        const float* wp = W + (size_t)(k0+kl)*ldw + wcol + n;
        rb[p][0] = wp[0]; rb[p][1] = wp[ldw];
      } else if (n < 16){
        const float* wp = W + (size_t)n*1024 + k0 + kl;
        rb[p][0] = wp[0]; rb[p][1] = wp[1];
      } else { rb[p][0]=0.f; rb[p][1]=0.f; }
    }
  };
  auto storeB = [&](){
    #pragma unroll
    for (int p=0;p<4;++p){
      int kl = p*16 + kp*2;
      unsigned pk = (unsigned)f2bf(rb[p][0]) | ((unsigned)f2bf(rb[p][1])<<16);
      *(unsigned*)&lB[swz128(n,kl)] = pk;
    }
  };

  loadA(kt0); loadB(kt0);
  for (int kb=0; kb<kIters; ++kb){
    storeA(); storeB();
    __syncthreads();
    if (kb+1 < kIters){ loadA(kt0+(kb+1)*64); loadB(kt0+(kb+1)*64); }
    mfma_step2(lA, lB, acc);
    __syncthreads();
  }
}

__device__ __forceinline__ void epi_atomic(f32x4 (&acc)[2][2], float* __restrict__ out,
                                           int ldo, int ocol, int nvalid){
  int tid=threadIdx.x, lane=tid&63, w=tid>>6, lo=lane&15, hi=lane>>4;
  #pragma unroll
  for (int mf=0;mf<2;++mf)
  #pragma unroll
  for (int nf=0;nf<2;++nf){
    int cl = nf*16 + lo;
    if (cl < nvalid){
      #pragma unroll
      for (int i=0;i<4;++i){
        int row = w*32 + mf*16 + hi*4 + i;
        unsafeAtomicAdd(&out[(size_t)row*ldo + ocol + cl], acc[mf][nf][i]);
      }
    }
  }
}

// ---------------- time-mix prep: LN + 8-way lerp -> bf16 mixed[8][B][C] ----------------
__launch_bounds__(256)
__global__ void tmix_prep(const float* __restrict__ x, const float* __restrict__ lnw,
                          const float* __restrict__ lnb, const float* __restrict__ lerp8,
                          const float* __restrict__ xs, unsigned short* __restrict__ mixed){
  int b = blockIdx.x, tid = threadIdx.x;
  f32x4 v = ((const f32x4*)(x + b*C_))[tid];
  float s  = v[0]+v[1]+v[2]+v[3];
  float ss = v[0]*v[0]+v[1]*v[1]+v[2]*v[2]+v[3]*v[3];
  __shared__ float red[8];
  s = wsum(s); ss = wsum(ss);
  int lane = tid&63, wv = tid>>6;
  if (lane==0){ red[wv]=s; red[4+wv]=ss; }
  __syncthreads();
  float S1 = red[0]+red[1]+red[2]+red[3];
  float S2 = red[4]+red[5]+red[6]+red[7];
  float m = S1*(1.f/C_);
  float var = S2*(1.f/C_) - m*m;
  float inv = rsqrtf(var + 1e-5f);
  int c0 = tid*4;
  float xl[4], xsv[4];
  #pragma unroll
  for(int j=0;j<4;++j){
    xl[j]  = (v[j]-m)*inv*lnw[c0+j] + lnb[c0+j];
    xsv[j] = xs[b*C_ + c0 + j];
  }
  #pragma unroll
  for(int jj=0;jj<8;++jj){
    float o[4];
    #pragma unroll
    for(int j=0;j<4;++j){
      float t = lerp8[jj*C_ + c0 + j];
      o[j] = xl[j] + t*(xsv[j]-xl[j]);
    }
    *(unsigned long long*)&mixed[jj*(B_*C_) + b*C_ + c0] = pack4(o[0],o[1],o[2],o[3]);
  }
}

// ---------------- channel-mix prep ----------------
__launch_bounds__(256)
__global__ void cmix_prep(const float* __restrict__ x, const float* __restrict__ lnw,
                          const float* __restrict__ lnb, const float* __restrict__ lk,
                          const float* __restrict__ xs, unsigned short* __restrict__ out){
  int b = blockIdx.x, tid = threadIdx.x;
  f32x4 v = ((const f32x4*)(x + b*C_))[tid];
  float s  = v[0]+v[1]+v[2]+v[3];
  float ss = v[0]*v[0]+v[1]*v[1]+v[2]*v[2]+v[3]*v[3];
  __shared__ float red[8];
  s = wsum(s); ss = wsum(ss);
  int lane = tid&63, wv = tid>>6;
  if (lane==0){ red[wv]=s; red[4+wv]=ss; }
  __syncthreads();
  float S1 = red[0]+red[1]+red[2]+red[3];
  float S2 = red[4]+red[5]+red[6]+red[7];
  float m = S1*(1.f/C_);
  float var = S2*(1.f/C_) - m*m;
  float inv = rsqrtf(var + 1e-5f);
  int c0 = tid*4;
  float o[4];
  #pragma unroll
  for(int j=0;j<4;++j){
    float xl = (v[j]-m)*inv*lnw[c0+j] + lnb[c0+j];
    float t = lk[c0+j];
    o[j] = xl + t*(xs[b*C_+c0+j]-xl);
  }
  *(unsigned long long*)&out[b*C_ + c0] = pack4(o[0],o[1],o[2],o[3]);
}

// ---------------- GEMM1: r/k/v + LoRA-A stage1 + ks/vs (107 tiles x 4 K-splits) ----------------
struct G1Args { const unsigned short* mixed; const float* W[9]; float* out; };

__launch_bounds__(256,4)
__global__ void gemm1_k(G1Args a){
  __shared__ unsigned short lA[128*64];
  __shared__ unsigned short lB[32*128];
  int t = blockIdx.x;
  int wsel, asel, wcol=0, ldw=1024, ocol, wtrans=0, nvalid=32;
  if (t < 96)      { int g=t>>5, s=t&31; wsel=g; asel=g; wcol=s*32; ocol=g*1024+s*32; }
  else if (t==96)  { wsel=3; asel=2; ldw=32;  ocol=3072; }
  else if (t<=98)  { int s=t-97;  wsel=4; asel=4; ldw=64;  wcol=s*32; ocol=3104+s*32; }
  else if (t<=100) { int s=t-99;  wsel=5; asel=3; ldw=64;  wcol=s*32; ocol=3168+s*32; }
  else if (t<=104) { int s=t-101; wsel=6; asel=5; ldw=128; wcol=s*32; ocol=3232+s*32; }
  else if (t==105) { wsel=7; asel=6; wtrans=1; nvalid=16; ocol=3360; }
  else             { wsel=8; asel=7; wtrans=1; nvalid=16; ocol=3376; }
  f32x4 acc[2][2] = {};
  gemm_pipe<0>(lA,lB, a.mixed + asel*(B_*C_), C_, a.W[wsel], ldw, wcol, wtrans,
               blockIdx.y*256, 4, acc);
  epi_atomic(acc, a.out, LD1, ocol, nvalid);
}

// ---------------- GEMM2: LoRA-B stage, single shot, fused nonlin + epilogues ----------------
struct G2Args {
  const float* g1; const float* vB; const float* aB; const float* dB; const float* gB;
  const float* vbias; const float* abias; const float* dbias;
  float *vm,*afin,*wfin,*gfin;
};

__launch_bounds__(256)
__global__ void gemm2_k(G2Args a){
  __shared__ unsigned short lA[128*128];
  __shared__ unsigned short lB[32*128];
  int t = blockIdx.x;
  int grp = t>>5, s = t&31;
  int Kd, acol, aop; const float* W;
  if (grp==0){ Kd=32;  acol=3072; aop=0; W=a.vB; }
  else if (grp==1){ Kd=64; acol=3104; aop=0; W=a.aB; }
  else if (grp==2){ Kd=64; acol=3168; aop=1; W=a.dB; }
  else { Kd=128; acol=3232; aop=2; W=a.gB; }
  int wcol = s*32;
  int tid = threadIdx.x, lane = tid&63, w = tid>>6, lo = lane&15, hi = lane>>4;
  #pragma unroll
  for (int p=0;p<16;++p){
    int idx = tid + p*256; int m = idx>>5; int c4 = (idx&31)<<2;
    unsigned long long val = 0ull;
    if (c4 < Kd){
      f32x4 v = *(const f32x4*)&a.g1[(size_t)m*LD1 + acol + c4];
      float e0=v[0],e1=v[1],e2=v[2],e3=v[3];
      if (aop==1){ e0=tanhf(e0); e1=tanhf(e1); e2=tanhf(e2); e3=tanhf(e3); }
      else if (aop==2){ e0=sigm(e0); e1=sigm(e1); e2=sigm(e2); e3=sigm(e3); }
      val = pack4(e0,e1,e2,e3);
    }
    *(unsigned long long*)&lA[swz128(m,c4)] = val;
  }
  int n = tid&31, kp = tid>>5;
  #pragma unroll
  for (int p=0;p<8;++p){
    int kl = p*16 + kp*2;
    float w0=0.f, w1=0.f;
    if (kl < Kd){ const float* wp = W + (size_t)kl*1024 + wcol + n; w0 = wp[0]; w1 = wp[1024]; }
    unsigned pk = (unsigned)f2bf(w0) | ((unsigned)f2bf(w1)<<16);
    *(unsigned*)&lB[swz128(n,kl)] = pk;
  }
  __syncthreads();
  f32x4 acc[2][2] = {};
  #pragma unroll
  for (int ks=0;ks<4;++ks){
    int kk = ks*32 + hi*8;
    bf16x8 a0 = *(const bf16x8*)&lA[swz128(w*32+lo, kk)];
    bf16x8 a1 = *(const bf16x8*)&lA[swz128(w*32+16+lo, kk)];
    #pragma unroll
    for (int nf=0;nf<2;++nf){
      bf16x8 b = *(const bf16x8*)&lB[swz128(nf*16+lo, kk)];
      acc[0][nf] = __builtin_amdgcn_mfma_f32_16x16x32_bf16(a0,b,acc[0][nf],0,0,0);
      acc[1][nf] = __builtin_amdgcn_mfma_f32_16x16x32_bf16(a1,b,acc[1][nf],0,0,0);
    }
  }
  #pragma unroll
  for (int mf=0;mf<2;++mf)
  #pragma unroll
  for (int nf=0;nf<2;++nf)
  #pragma unroll
  for (int i=0;i<4;++i){
    int row = w*32+mf*16+hi*4+i;
    int c = wcol + nf*16 + lo;
    float x = acc[mf][nf][i];
    int o = row*C_ + c;
    if (grp==3){ a.gfin[o] = x; }
    else if (grp==1){ a.afin[o] = sigm(x + a.abias[c]); }
    else if (grp==2){
      float d = x + a.dbias[c];
      float sp = log1pf(expf(-d));
      a.wfin[o] = expf(-expf(-0.5f - sp));
    } else {
      a.vm[o] = sigm(x + a.vbias[c]);
    }
  }
}

// ---------------- state kernel: one wave per (b,h) ----------------
__launch_bounds__(256)
__global__ void state_k(const float* __restrict__ g1, const float* __restrict__ vm,
                        const float* __restrict__ afin, const float* __restrict__ wfin,
                        const float* __restrict__ gfin, const float* __restrict__ S,
                        const float* __restrict__ bon, const float* __restrict__ ksb,
                        const float* __restrict__ vsb, const float* __restrict__ gnw,
                        const float* __restrict__ gnb, float* __restrict__ v0,
                        int first, unsigned short* __restrict__ y){
  __shared__ __align__(16) float lt[4][2][64];
  int wv = threadIdx.x>>6, lane = threadIdx.x&63;
  int pair = blockIdx.x*4 + wv;
  int b = pair>>4, h = pair&15;
  const float* g1r = g1 + (size_t)b*LD1;
  int ci = h*64 + lane;
  float r   = g1r[ci];
  float k   = g1r[1024+ci];
  float vwv = g1r[2048+ci];
  float v;
  if (first){ v = vwv; v0[b*C_+ci] = vwv; }
  else { float vmv = vm[b*C_+ci]; v = vwv + vmv*(v0[b*C_+ci] - vwv); }
  float aa = afin[b*C_+ci];
  float ww = wfin[b*C_+ci];
  float gg = gfin[b*C_+ci];
  float ks = sigm(g1r[3360+h] + ksb[h]);
  float vs = sigm(g1r[3376+h] + vsb[h]);
  float nk = sqrtf(wsum(k*k));
  float kkv = ks * k / fmaxf(nk, 1e-12f);
  float nv = sqrtf(wsum(v*v));
  float vh = vs * v / fmaxf(nv, 1e-12f);
  float kh = kkv * aa;
  float khrh = wsum(kh*r);
  float bkr  = wsum(r * bon[h*64+lane] * kh);
  lt[wv][0][lane] = ww*r;
  lt[wv][1][lane] = kkv;
  __syncthreads();
  const float* Sr = S + ((size_t)((b*16+h)*64 + lane))*64;
  float s1=0.f, s2=0.f;
  #pragma unroll
  for (int j=0;j<16;++j){
    f32x4 sv = *(const f32x4*)&Sr[j*4];
    f32x4 u1 = *(const f32x4*)&lt[wv][0][j*4];
    f32x4 u2 = *(const f32x4*)&lt[wv][1][j*4];
    s1 += sv[0]*u1[0]+sv[1]*u1[1]+sv[2]*u1[2]+sv[3]*u1[3];
    s2 += sv[0]*u2[0]+sv[1]*u2[1]+sv[2]*u2[2]+sv[3]*u2[3];
  }
  float out = s1 + (vh - s2)*khrh;
  float mu = wsum(out)*(1.f/64.f);
  float dev = out - mu;
  float var = wsum(dev*dev)*(1.f/64.f);
  float gn = dev*rsqrtf(var + 6.4e-4f)*gnw[ci] + gnb[ci];
  float yv = gg*(gn + bkr*vh);
  y[b*C_+ci] = f2bf(yv);
}

// ---------------- Wo GEMM: split-K 4, atomic add onto residual ----------------
__launch_bounds__(256,4)
__global__ void wo_k(const unsigned short* __restrict__ y, const float* __restrict__ W,
                     float* __restrict__ xbuf){
  __shared__ unsigned short lA[128*64];
  __shared__ unsigned short lB[32*128];
  f32x4 acc[2][2] = {};
  gemm_pipe<0>(lA,lB, y, 1024, W, 1024, blockIdx.x*32, 0, blockIdx.y*256, 4, acc);
  epi_atomic(acc, xbuf, 1024, blockIdx.x*32, 32);
}

// ---------------- cW_k GEMM: split-K 2, atomic add into hbuf ----------------
__launch_bounds__(256,4)
__global__ void cwk_k(const unsigned short* __restrict__ A, const float* __restrict__ W,
                      float* __restrict__ hbuf){
  __shared__ unsigned short lA[128*64];
  __shared__ unsigned short lB[32*128];
  f32x4 acc[2][2] = {};
  gemm_pipe<0>(lA,lB, A, 1024, W, 4096, blockIdx.x*32, 0, blockIdx.y*512, 8, acc);
  epi_atomic(acc, hbuf, 4096, blockIdx.x*32, 32);
}

// ---------------- cW_v GEMM: A=f32 hbuf with fused relu^2; split-K 8; add to residual ----------------
__launch_bounds__(256,4)
__global__ void cwv_k(const float* __restrict__ A, const float* __restrict__ W,
                      float* __restrict__ xbuf){
  __shared__ unsigned short lA[128*64];
  __shared__ unsigned short lB[32*128];
  f32x4 acc[2][2] = {};
  gemm_pipe<1>(lA,lB, A, 4096, W, 1024, blockIdx.x*32, 0, blockIdx.y*512, 8, acc);
  epi_atomic(acc, xbuf, 1024, blockIdx.x*32, 32);
}

extern "C" void kernel_launch(void* const* d_in, const int* in_sizes, int n_in,
                              void* d_out, int out_size, void* d_ws, size_t ws_size,
                              hipStream_t stream){
  const float* in_BC  = (const float*)d_in[0];
  const float* txs    = (const float*)d_in[1];
  const float* tstate = (const float*)d_in[2];
  const float* cxs    = (const float*)d_in[3];
  const float* lntw   = (const float*)d_in[4];
  const float* lntb   = (const float*)d_in[5];
  const float* lerp8  = (const float*)d_in[6];
  const float* bon    = (const float*)d_in[7];
  const float* Wr     = (const float*)d_in[8];
  const float* Wk     = (const float*)d_in[9];
  const float* Wv     = (const float*)d_in[10];
  const float* Wo     = (const float*)d_in[11];
  const float* ksW    = (const float*)d_in[12];
  const float* ksb    = (const float*)d_in[13];
  const float* vsW    = (const float*)d_in[14];
  const float* vsb    = (const float*)d_in[15];
  const float* vA     = (const float*)d_in[16];
  const float* vBp    = (const float*)d_in[17];
  const float* vbias  = (const float*)d_in[18];
  const float* aA     = (const float*)d_in[19];
  const float* aB     = (const float*)d_in[20];
  const float* abias  = (const float*)d_in[21];
  const float* dA     = (const float*)d_in[22];
  const float* dB     = (const float*)d_in[23];
  const float* dbias  = (const float*)d_in[24];
  const float* gA     = (const float*)d_in[25];
  const float* gB     = (const float*)d_in[26];
  const float* gnw    = (const float*)d_in[27];
  const float* gnb    = (const float*)d_in[28];
  const float* lncw   = (const float*)d_in[29];
  const float* lncb   = (const float*)d_in[30];
  const float* lkc    = (const float*)d_in[31];
  const float* cWk    = (const float*)d_in[32];
  const float* cWv    = (const float*)d_in[33];

  char* ws = (char*)d_ws;
  float* xbuf           = (float*)(ws + 0x000000);          // 512K f32 residual
  unsigned short* mixed = (unsigned short*)(ws + 0x080000); // 2M bf16 (8,B,C)
  float* g1o            = (float*)(ws + 0x280000);          // (B,3392) f32 = 0x1A8000
  float* hbuf           = (float*)(ws + 0x428000);          // 2M f32 (B,4096)
  float* vm             = (float*)(ws + 0x628000);          // 512K
  float* afin           = (float*)(ws + 0x6A8000);          // 512K
  float* wfin           = (float*)(ws + 0x728000);          // 512K
  float* gfin           = (float*)(ws + 0x7A8000);          // 512K
  float* v0             = (float*)(ws + 0x828000);          // 512K
  unsigned short* ybuf  = (unsigned short*)(ws + 0x8A8000); // 256K bf16
  unsigned short* mixc  = (unsigned short*)(ws + 0x8E8000); // 256K bf16

  hipMemcpyAsync(xbuf, in_BC, 524288, hipMemcpyDeviceToDevice, stream);
  for (int l=0; l<12; ++l){
    hipMemsetAsync(g1o, 0, 0x3A8000, stream);   // zeros g1o + hbuf (contiguous)
    tmix_prep<<<128,256,0,stream>>>(xbuf, lntw+l*1024, lntb+l*1024, lerp8+l*8192,
                                    txs+l*131072, mixed);
    G1Args a1;
    a1.mixed = mixed;
    a1.W[0] = Wr + (size_t)l*1048576; a1.W[1] = Wk + (size_t)l*1048576; a1.W[2] = Wv + (size_t)l*1048576;
    a1.W[3] = vA + l*32768; a1.W[4] = aA + l*65536; a1.W[5] = dA + l*65536; a1.W[6] = gA + l*131072;
    a1.W[7] = ksW + l*16384; a1.W[8] = vsW + l*16384;
    a1.out = g1o;
    gemm1_k<<<dim3(107,4),256,0,stream>>>(a1);
    G2Args a2;
    a2.g1 = g1o; a2.vB = vBp + l*32768; a2.aB = aB + l*65536; a2.dB = dB + l*65536; a2.gB = gB + l*131072;
    a2.vbias = vbias + l*1024; a2.abias = abias + l*1024; a2.dbias = dbias + l*1024;
    a2.vm = vm; a2.afin = afin; a2.wfin = wfin; a2.gfin = gfin;
    gemm2_k<<<128,256,0,stream>>>(a2);
    state_k<<<512,256,0,stream>>>(g1o, vm, afin, wfin, gfin,
                                  tstate + (size_t)l*8388608, bon + l*1024,
                                  ksb + l*16, vsb + l*16, gnw + l*1024, gnb + l*1024,
                                  v0, (l==0)?1:0, ybuf);
    wo_k<<<dim3(32,4),256,0,stream>>>(ybuf, Wo + (size_t)l*1048576, xbuf);
    cmix_prep<<<128,256,0,stream>>>(xbuf, lncw+l*1024, lncb+l*1024, lkc+l*1024,
                                    cxs+l*131072, mixc);
    cwk_k<<<dim3(128,2),256,0,stream>>>(mixc, cWk + (size_t)l*4194304, hbuf);
    cwv_k<<<dim3(32,8),256,0,stream>>>(hbuf, cWv + (size_t)l*4194304, xbuf);
  }
  hipMemcpyAsync(d_out, xbuf, 524288, hipMemcpyDeviceToDevice, stream);
}